// Round 3
// baseline (165.195 us; speedup 1.0000x reference)
//
#include <hip/hip_runtime.h>
#include <math.h>

#define B_ 4
#define S_ 2048
#define G_ 8
#define D_ 128
#define N_ 64
#define ROWS (B_*S_*G_)      // 65536
#define CH 64
#define CLEN 32
#define NCHAIN (B_*G_*N_)    // 2048
#define YOFF (ROWS*D_)       // 8388608

typedef short bf16x8 __attribute__((ext_vector_type(8)));
typedef float f32x4  __attribute__((ext_vector_type(4)));
#define MFMA16(a,b,c) __builtin_amdgcn_mfma_f32_16x16x32_bf16(a,b,c,0,0,0)

__device__ __forceinline__ unsigned short bf16_rtne(float f) {
    unsigned u = __float_as_uint(f);
    unsigned r = (u + 0x7FFFu + ((u >> 16) & 1u)) >> 16;
    return (unsigned short)r;
}
__device__ __forceinline__ void split_bf16(float f, unsigned short &hi, unsigned short &lo) {
    hi = bf16_rtne(f);
    float hif = __uint_as_float(((unsigned)hi) << 16);
    lo = bf16_rtne(f - hif);
}
// fast split via v_cvt_pk_bf16_f32 (RTNE, 2 floats -> packed 2xbf16 in 1 instr)
__device__ __forceinline__ unsigned pk_bf16(float a, float b) {
    unsigned r;
    asm("v_cvt_pk_bf16_f32 %0, %1, %2" : "=v"(r) : "v"(a), "v"(b));
    return r;
}
__device__ __forceinline__ void split4_pk(float4 v, uint2 &hi2, uint2 &lo2) {
    unsigned p0 = pk_bf16(v.x, v.y);
    unsigned p1 = pk_bf16(v.z, v.w);
    float r0 = v.x - __uint_as_float(p0 << 16);
    float r1 = v.y - __uint_as_float(p0 & 0xFFFF0000u);
    float r2 = v.z - __uint_as_float(p1 << 16);
    float r3 = v.w - __uint_as_float(p1 & 0xFFFF0000u);
    hi2 = make_uint2(p0, p1);
    lo2 = make_uint2(pk_bf16(r0, r1), pk_bf16(r2, r3));
}
__device__ __forceinline__ float dot4(float4 a, float4 b) {
    return fmaf(a.x,b.x, fmaf(a.y,b.y, fmaf(a.z,b.z, a.w*b.w)));
}

// ============ k_prep: pre-split weights into MFMA fragment order ============
// B weights: K = [x_r(128), x_i(128)] (unchanged).
// C weights: K INTERLEAVED as (hr_n, hi_n) pairs: k=2n -> hr part, k=2n+1 -> hi.
__global__ __launch_bounds__(256) void k_prep(
    const float* __restrict__ bwr, const float* __restrict__ bwi,
    const float* __restrict__ cwr, const float* __restrict__ cwi,
    unsigned short* __restrict__ wbhi, unsigned short* __restrict__ wblo,
    unsigned short* __restrict__ wchi)
{
    int tid = blockIdx.x * 256 + threadIdx.x;   // [0, 8192)
    if (tid < 4096) {
        int f = tid;
        int lane = f & 63, ks = (f >> 6) & 7, nt = (f >> 9) & 1, w = f >> 10;
        int l15 = lane & 15, quad = lane >> 4;
        int n = w * 32 + nt * 16 + l15;
        int k0 = ks * 32 + quad * 8;
        const float* src; float sgn = 1.f;
        if (n < 64) {
            if (k0 < 128) src = bwr + n * 128 + k0;
            else        { src = bwi + n * 128 + (k0 - 128); sgn = -1.f; }
        } else {
            if (k0 < 128) src = bwi + (n - 64) * 128 + k0;
            else          src = bwr + (n - 64) * 128 + (k0 - 128);
        }
        float4 v0 = *(const float4*)src;
        float4 v1 = *(const float4*)(src + 4);
        float vv[8] = {v0.x,v0.y,v0.z,v0.w,v1.x,v1.y,v1.z,v1.w};
        unsigned short h[8], l[8];
        #pragma unroll
        for (int j = 0; j < 8; j++) split_bf16(vv[j] * sgn, h[j], l[j]);
        #pragma unroll
        for (int j = 0; j < 8; j++) { wbhi[f*8+j] = h[j]; wblo[f*8+j] = l[j]; }
    } else {
        int f = tid - 4096;
        int lane = f & 63, ks = (f >> 6) & 3, nt = (f >> 8) & 3, w = f >> 10;
        int l15 = lane & 15, quad = lane >> 4;
        int n = w * 64 + nt * 16 + l15;
        int d = (n < 128) ? n : (n - 128);
        int k0 = ks * 32 + quad * 8;
        unsigned short h[8];
        #pragma unroll
        for (int j = 0; j < 8; j++) {
            int k = k0 + j, col = k >> 1;
            float val;
            if (n < 128) val = (k & 1) ? -cwi[d * 64 + col] : cwr[d * 64 + col];
            else         val = (k & 1) ?  cwr[d * 64 + col] : cwi[d * 64 + col];
            unsigned short hh, hl; split_bf16(val, hh, hl);
            h[j] = hh;
        }
        #pragma unroll
        for (int j = 0; j < 8; j++) wchi[f*8+j] = h[j];
    }
}

// ============ G1: fused dt + Bx GEMM + chunk-transition compose =============
// ONE chunk (32 steps) per block; grid = 32 bg * 64 chunks = 2048 blocks.
// bx/dt written CHUNK-MAJOR: bx[(bg*CH+c)*CLEN + tt][n], dt[(bg*CH+c)*CLEN+tt].
#define LDK1 280
__global__ __launch_bounds__(256, 4) void k_g1(
    const float* __restrict__ xr, const float* __restrict__ xi,
    const float* __restrict__ dtw, const float* __restrict__ dtb,
    const float* __restrict__ logAm, const float* __restrict__ Aph,
    const unsigned short* __restrict__ wbhi, const unsigned short* __restrict__ wblo,
    float* __restrict__ bxr, float* __restrict__ bxi,
    float* __restrict__ dt_mag, float* __restrict__ dt_ph,
    float4* __restrict__ trans)
{
    __shared__ __align__(16) unsigned short Ahi[32 * LDK1];
    __shared__ __align__(16) unsigned short Alo[32 * LDK1];
    __shared__ float dms[32], dps[32];
    __shared__ float4 comb[64];
    float* bxs = (float*)Ahi;   // reused after MFMA reads
    const int t = threadIdx.x;
    const int lane = t & 63, w = t >> 6;
    const int l15 = lane & 15, quad = lane >> 4;
    const int bg = blockIdx.x >> 6, c = blockIdx.x & 63;
    const int g = bg & 7, b = bg >> 3;
    const int crow = (bg * CH + c) * CLEN;   // chunk-major row base

    const int kq = t & 31, k4 = kq * 4;
    float4 w0r = *(const float4*)(dtw + k4);
    float4 w0i = *(const float4*)(dtw + 128 + k4);
    float4 w1r = *(const float4*)(dtw + 256 + k4);
    float4 w1i = *(const float4*)(dtw + 384 + k4);
    float b0 = dtb[0], b1 = dtb[1];
    float nla = -logf(1.0f + __expf(logAm[g * N_ + lane]));
    float aph = Aph[g * N_ + lane];

    const int s0 = c * CLEN;
    const float* xrb = xr + ((size_t)(b * S_ + s0) * G_ + g) * 128;
    const float* xib = xi + ((size_t)(b * S_ + s0) * G_ + g) * 128;

    // -------- stage x -> LDS (bf16 hi/lo via cvt_pk) + dt partial dots ------
    float pm[4], pp[4];
    #pragma unroll
    for (int i = 0; i < 4; i++) {
        int f = t + 256 * i;
        int m = f >> 5, kk = f & 31;
        float4 a  = ((const float4*)(xrb + m * 1024))[kk];
        float4 bb = ((const float4*)(xib + m * 1024))[kk];
        uint2 h2, l2;
        split4_pk(a, h2, l2);
        *(uint2*)&Ahi[m * LDK1 + kk * 4] = h2;
        *(uint2*)&Alo[m * LDK1 + kk * 4] = l2;
        split4_pk(bb, h2, l2);
        *(uint2*)&Ahi[m * LDK1 + 128 + kk * 4] = h2;
        *(uint2*)&Alo[m * LDK1 + 128 + kk * 4] = l2;
        pm[i] = dot4(a, w0r) + dot4(bb, w0i);
        pp[i] = dot4(a, w1r) + dot4(bb, w1i);
    }
    #pragma unroll
    for (int i = 0; i < 4; i++) {
        float vm = pm[i], vp = pp[i];
        #pragma unroll
        for (int msk = 16; msk >= 1; msk >>= 1) {
            vm += __shfl_xor(vm, msk);
            vp += __shfl_xor(vp, msk);
        }
        if ((t & 31) == 0) {
            int m = (t >> 5) + 8 * i;
            float dm = fminf(fmaxf(__expf(vm + b0), 1e-4f), 2.0f);
            float dp = fminf(fmaxf(__expf(vp + b1), 1e-4f), 2.0f);
            dms[m] = dm; dps[m] = dp;
            dt_mag[crow + m] = dm; dt_ph[crow + m] = dp;
        }
    }
    __syncthreads();

    // -------- Bx GEMM: stream W fragments from L2 per ks --------
    f32x4 acc[2][2];
    #pragma unroll
    for (int a = 0; a < 2; a++)
        #pragma unroll
        for (int bq = 0; bq < 2; bq++)
            acc[a][bq] = (f32x4){0.f, 0.f, 0.f, 0.f};
    #pragma unroll
    for (int ks = 0; ks < 8; ks++) {
        bf16x8 wh0 = ((const bf16x8*)wbhi)[((w * 2 + 0) * 8 + ks) * 64 + lane];
        bf16x8 wl0 = ((const bf16x8*)wblo)[((w * 2 + 0) * 8 + ks) * 64 + lane];
        bf16x8 wh1 = ((const bf16x8*)wbhi)[((w * 2 + 1) * 8 + ks) * 64 + lane];
        bf16x8 wl1 = ((const bf16x8*)wblo)[((w * 2 + 1) * 8 + ks) * 64 + lane];
        #pragma unroll
        for (int ms = 0; ms < 2; ms++) {
            int arow = (ms * 16 + l15) * LDK1 + quad * 8;
            bf16x8 ah = *(const bf16x8*)&Ahi[arow + ks * 32];
            bf16x8 al = *(const bf16x8*)&Alo[arow + ks * 32];
            acc[ms][0] = MFMA16(al, wh0, acc[ms][0]);
            acc[ms][0] = MFMA16(ah, wl0, acc[ms][0]);
            acc[ms][0] = MFMA16(ah, wh0, acc[ms][0]);
            acc[ms][1] = MFMA16(al, wh1, acc[ms][1]);
            acc[ms][1] = MFMA16(ah, wl1, acc[ms][1]);
            acc[ms][1] = MFMA16(ah, wh1, acc[ms][1]);
        }
    }
    __syncthreads();   // staging reads done; Ahi region becomes bxs

    // -------- store Bx (chunk-major, dense 8KB/chunk) + LDS ----------------
    #pragma unroll
    for (int ms = 0; ms < 2; ms++)
        #pragma unroll
        for (int nt = 0; nt < 2; nt++) {
            int n = w * 32 + nt * 16 + l15;
            float* dstg = (n < 64) ? bxr : bxi;
            int nn = n & 63;
            #pragma unroll
            for (int r = 0; r < 4; r++) {
                int m = ms * 16 + quad * 4 + r;
                float v = acc[ms][nt][r] * dms[m];
                dstg[(crow + m) * 64 + nn] = v;
                bxs[m * 132 + n] = v;
            }
        }
    __syncthreads();

    // -------- compose chunk transition: wave 0 = steps 0..15, wave 1 = 16..31
    float Ar = 1.f, Ai = 0.f, Br = 0.f, Bi = 0.f;
    if (w < 2) {
        int base = w * 16;
        #pragma unroll
        for (int tt = 0; tt < 16; tt++) {
            int m = base + tt;
            float dm = dms[m], dp = dps[m];
            float am  = __expf(dm * nla);
            float ang = dp * aph;
            float cr = am * __cosf(ang), ci = am * __sinf(ang);
            float vr = bxs[m * 132 + lane], vi = bxs[m * 132 + 64 + lane];
            float nAr = cr * Ar - ci * Ai;
            float nAi = cr * Ai + ci * Ar;
            float nBr = cr * Br - ci * Bi + vr;
            float nBi = cr * Bi + ci * Br + vi;
            Ar = nAr; Ai = nAi; Br = nBr; Bi = nBi;
        }
        if (w == 0) comb[lane] = make_float4(Ar, Ai, Br, Bi);
    }
    __syncthreads();
    if (w == 1) {
        float4 c0 = comb[lane];
        float fAr = Ar * c0.x - Ai * c0.y;
        float fAi = Ar * c0.y + Ai * c0.x;
        float fBr = Ar * c0.z - Ai * c0.w + Br;
        float fBi = Ar * c0.w + Ai * c0.z + Bi;
        trans[(bg * CH + c) * 64 + lane] = make_float4(fAr, fAi, fBr, fBi);
    }
}

// ============ scanB2: parallel chunk-level combine ==========================
__global__ __launch_bounds__(256) void k_scanB2(const float4* __restrict__ trans,
    float2* __restrict__ hstart)
{
    int w = threadIdx.x >> 6, lane = threadIdx.x & 63;
    int W = blockIdx.x * 4 + w;              // [0,256)
    int bg = W >> 3;
    int n  = ((W & 7) << 3) + (lane & 7);
    int j  = lane >> 3;                       // segment index
    float pAr[8], pAi[8], pBr[8], pBi[8];
    float Ar = 1.f, Ai = 0.f, Br = 0.f, Bi = 0.f;
    const float4* tp = trans + (bg * CH + j * 8) * 64 + n;
    #pragma unroll
    for (int k = 0; k < 8; k++) {
        pAr[k] = Ar; pAi[k] = Ai; pBr[k] = Br; pBi[k] = Bi;
        float4 T = tp[k * 64];
        float nAr = T.x * Ar - T.y * Ai;
        float nAi = T.x * Ai + T.y * Ar;
        float nBr = T.x * Br - T.y * Bi + T.z;
        float nBi = T.x * Bi + T.y * Br + T.w;
        Ar = nAr; Ai = nAi; Br = nBr; Bi = nBi;
    }
    float hr = 0.f, hi = 0.f, mhr = 0.f, mhi = 0.f;
    #pragma unroll
    for (int j2 = 0; j2 < 8; j2++) {
        if (j2 == j) { mhr = hr; mhi = hi; }
        int src = j2 * 8 + (lane & 7);
        float sAr = __shfl(Ar, src), sAi = __shfl(Ai, src);
        float sBr = __shfl(Br, src), sBi = __shfl(Bi, src);
        float nr = sAr * hr - sAi * hi + sBr;
        float ni = sAr * hi + sAi * hr + sBi;
        float nrm = sqrtf(nr * nr + ni * ni + 1e-8f);
        float sc = fminf(nrm, 100.f) / nrm;
        hr = nr * sc; hi = ni * sc;
    }
    float2* hp = hstart + (bg * CH + j * 8) * 64 + n;
    #pragma unroll
    for (int k = 0; k < 8; k++) {
        float hsr = pAr[k] * mhr - pAi[k] * mhi + pBr[k];
        float hsi = pAr[k] * mhi + pAi[k] * mhr + pBi[k];
        hp[k * 64] = make_float2(hsr, hsi);
    }
}

// ============ SG2: fused scanC + y GEMM =====================================
// ONE chunk (32 rows) per block; grid = 32 bg * 64 = 2048 blocks, 6 blocks/CU.
// K interleaved (hr_n, hi_n): scan writes ONE packed b32 per LDS array/step.
#define LDK2 152
__global__ __launch_bounds__(256, 6) void k_sg2(
    const float* __restrict__ bxr, const float* __restrict__ bxi,
    const float* __restrict__ dt_mag, const float* __restrict__ dt_ph,
    const float* __restrict__ logAm, const float* __restrict__ Aph,
    const float2* __restrict__ hstart,
    const unsigned short* __restrict__ wchi,
    float* __restrict__ out)
{
    __shared__ __align__(16) unsigned short Ahi[32 * LDK2];
    __shared__ __align__(16) unsigned short Alo[32 * LDK2];
    const int t = threadIdx.x;
    const int lane = t & 63, w = t >> 6;
    const int l15 = lane & 15, quad = lane >> 4;
    const int bg = blockIdx.x >> 6, c = blockIdx.x & 63;
    const int g = bg & 7, b = bg >> 3;

    // -------- within-chunk scan: wave 0, lane = n --------
    if (w == 0) {
        const int n = lane;
        float nla = -logf(1.0f + __expf(logAm[g * N_ + n]));
        float aph = Aph[g * N_ + n];
        float2 h0 = hstart[(bg * CH + c) * 64 + n];
        float hr = h0.x, hi = h0.y;
        const bool rn = ((c & 7) == 7);
        const int base = (bg * CH + c) * CLEN;
        #pragma unroll 8
        for (int tt = 0; tt < CLEN; tt++) {
            float dm = dt_mag[base + tt], dp = dt_ph[base + tt];
            float am  = __expf(dm * nla);
            float ang = dp * aph;
            float cr = am * __cosf(ang), ci = am * __sinf(ang);
            float vr = bxr[(base + tt) * 64 + n];
            float vi = bxi[(base + tt) * 64 + n];
            float nr = cr * hr - ci * hi + vr;
            float ni = cr * hi + ci * hr + vi;
            if (rn && tt == CLEN - 1) {
                float nrm = sqrtf(nr * nr + ni * ni + 1e-8f);
                float scale = fminf(nrm, 100.0f) / nrm;
                nr *= scale; ni *= scale;
            }
            hr = nr; hi = ni;
            unsigned hp = pk_bf16(hr, hi);
            float rr = hr - __uint_as_float(hp << 16);
            float ri = hi - __uint_as_float(hp & 0xFFFF0000u);
            unsigned lp = pk_bf16(rr, ri);
            *(unsigned*)&Ahi[tt * LDK2 + 2 * n] = hp;
            *(unsigned*)&Alo[tt * LDK2 + 2 * n] = lp;
        }
    }
    __syncthreads();

    // -------- y GEMM: M=32, N=256 split 4 waves x 4 nt, stream wc per ks ----
    f32x4 acc[2][4];
    #pragma unroll
    for (int a = 0; a < 2; a++)
        #pragma unroll
        for (int bq = 0; bq < 4; bq++)
            acc[a][bq] = (f32x4){0.f, 0.f, 0.f, 0.f};
    #pragma unroll
    for (int ks = 0; ks < 4; ks++) {
        bf16x8 wc0 = ((const bf16x8*)wchi)[((w * 4 + 0) * 4 + ks) * 64 + lane];
        bf16x8 wc1 = ((const bf16x8*)wchi)[((w * 4 + 1) * 4 + ks) * 64 + lane];
        bf16x8 wc2 = ((const bf16x8*)wchi)[((w * 4 + 2) * 4 + ks) * 64 + lane];
        bf16x8 wc3 = ((const bf16x8*)wchi)[((w * 4 + 3) * 4 + ks) * 64 + lane];
        #pragma unroll
        for (int ms = 0; ms < 2; ms++) {
            int arow = (ms * 16 + l15) * LDK2 + quad * 8;
            bf16x8 ah = *(const bf16x8*)&Ahi[arow + ks * 32];
            bf16x8 al = *(const bf16x8*)&Alo[arow + ks * 32];
            acc[ms][0] = MFMA16(al, wc0, acc[ms][0]);
            acc[ms][0] = MFMA16(ah, wc0, acc[ms][0]);
            acc[ms][1] = MFMA16(al, wc1, acc[ms][1]);
            acc[ms][1] = MFMA16(ah, wc1, acc[ms][1]);
            acc[ms][2] = MFMA16(al, wc2, acc[ms][2]);
            acc[ms][2] = MFMA16(ah, wc2, acc[ms][2]);
            acc[ms][3] = MFMA16(al, wc3, acc[ms][3]);
            acc[ms][3] = MFMA16(ah, wc3, acc[ms][3]);
        }
    }
    #pragma unroll
    for (int ms = 0; ms < 2; ms++)
        #pragma unroll
        for (int nt = 0; nt < 4; nt++) {
            int nn = w * 64 + nt * 16 + l15;
            float* dst = (nn < 128) ? (out + nn) : (out + YOFF + (nn - 128));
            #pragma unroll
            for (int r = 0; r < 4; r++) {
                int tt2 = ms * 16 + quad * 4 + r;
                int srow = (b * S_ + c * CLEN + tt2) * G_ + g;
                dst[srow * 128] = acc[ms][nt][r];
            }
        }
}

extern "C" void kernel_launch(void* const* d_in, const int* in_sizes, int n_in,
                              void* d_out, int out_size, void* d_ws, size_t ws_size,
                              hipStream_t stream) {
    (void)in_sizes; (void)n_in; (void)out_size; (void)ws_size;
    const float* xr    = (const float*)d_in[0];
    const float* xi    = (const float*)d_in[1];
    const float* logAm = (const float*)d_in[2];
    const float* Aph   = (const float*)d_in[3];
    const float* bwr   = (const float*)d_in[4];
    const float* bwi   = (const float*)d_in[5];
    const float* cwr   = (const float*)d_in[6];
    const float* cwi   = (const float*)d_in[7];
    const float* dtw   = (const float*)d_in[8];
    const float* dtb   = (const float*)d_in[9];
    float* out = (float*)d_out;
    float* ws  = (float*)d_ws;

    float*  dt_mag = ws;                      // 65536
    float*  dt_ph  = ws + 65536;              // 65536
    float*  bxr    = ws + 131072;             // 4194304
    float*  bxi    = bxr + 4194304;           // 4194304
    float4* trans  = (float4*)(ws + 8519680); // 131072 float4
    float2* hstart = (float2*)(ws + 9043968); // 131072 float2
    unsigned short* wbhi = (unsigned short*)(ws + 9306112); // 32768 shorts
    unsigned short* wblo = wbhi + 32768;
    unsigned short* wchi = wblo + 32768;

    hipLaunchKernelGGL(k_prep,   dim3(32), dim3(256), 0, stream,
                       bwr, bwi, cwr, cwi, wbhi, wblo, wchi);
    hipLaunchKernelGGL(k_g1,     dim3((B_ * G_) * 64), dim3(256), 0, stream,
                       xr, xi, dtw, dtb, logAm, Aph, wbhi, wblo,
                       bxr, bxi, dt_mag, dt_ph, trans);
    hipLaunchKernelGGL(k_scanB2, dim3(64), dim3(256), 0, stream,
                       trans, hstart);
    hipLaunchKernelGGL(k_sg2,    dim3((B_ * G_) * 64), dim3(256), 0, stream,
                       bxr, bxi, dt_mag, dt_ph, logAm, Aph, hstart, wchi, out);
}

// Round 4
// 160.319 us; speedup vs baseline: 1.0304x; 1.0304x over previous
//
#include <hip/hip_runtime.h>
#include <hip/hip_cooperative_groups.h>
#include <math.h>

namespace cg = cooperative_groups;

#define B_ 4
#define S_ 2048
#define G_ 8
#define D_ 128
#define N_ 64
#define ROWS (B_*S_*G_)      // 65536
#define CH 64
#define CLEN 32
#define YOFF (ROWS*D_)       // 8388608

typedef short bf16x8 __attribute__((ext_vector_type(8)));
typedef float f32x4  __attribute__((ext_vector_type(4)));
#define MFMA16(a,b,c) __builtin_amdgcn_mfma_f32_16x16x32_bf16(a,b,c,0,0,0)

__device__ __forceinline__ unsigned short bf16_rtne(float f) {
    unsigned u = __float_as_uint(f);
    unsigned r = (u + 0x7FFFu + ((u >> 16) & 1u)) >> 16;
    return (unsigned short)r;
}
__device__ __forceinline__ void split_bf16(float f, unsigned short &hi, unsigned short &lo) {
    hi = bf16_rtne(f);
    float hif = __uint_as_float(((unsigned)hi) << 16);
    lo = bf16_rtne(f - hif);
}
__device__ __forceinline__ unsigned pk_bf16(float a, float b) {
    unsigned r;
    asm("v_cvt_pk_bf16_f32 %0, %1, %2" : "=v"(r) : "v"(a), "v"(b));
    return r;
}
__device__ __forceinline__ void split4_pk(float4 v, uint2 &hi2, uint2 &lo2) {
    unsigned p0 = pk_bf16(v.x, v.y);
    unsigned p1 = pk_bf16(v.z, v.w);
    float r0 = v.x - __uint_as_float(p0 << 16);
    float r1 = v.y - __uint_as_float(p0 & 0xFFFF0000u);
    float r2 = v.z - __uint_as_float(p1 << 16);
    float r3 = v.w - __uint_as_float(p1 & 0xFFFF0000u);
    hi2 = make_uint2(p0, p1);
    lo2 = make_uint2(pk_bf16(r0, r1), pk_bf16(r2, r3));
}
__device__ __forceinline__ float dot4(float4 a, float4 b) {
    return fmaf(a.x,b.x, fmaf(a.y,b.y, fmaf(a.z,b.z, a.w*b.w)));
}

// ============ k_prep: pre-split weights into MFMA fragment order ============
// B weights: K = [x_r(128), x_i(128)].
// C weights: K INTERLEAVED as (hr_n, hi_n) pairs.
__global__ __launch_bounds__(256) void k_prep(
    const float* __restrict__ bwr, const float* __restrict__ bwi,
    const float* __restrict__ cwr, const float* __restrict__ cwi,
    unsigned short* __restrict__ wbhi, unsigned short* __restrict__ wblo,
    unsigned short* __restrict__ wchi)
{
    int tid = blockIdx.x * 256 + threadIdx.x;   // [0, 8192)
    if (tid < 4096) {
        int f = tid;
        int lane = f & 63, ks = (f >> 6) & 7, nt = (f >> 9) & 1, w = f >> 10;
        int l15 = lane & 15, quad = lane >> 4;
        int n = w * 32 + nt * 16 + l15;
        int k0 = ks * 32 + quad * 8;
        const float* src; float sgn = 1.f;
        if (n < 64) {
            if (k0 < 128) src = bwr + n * 128 + k0;
            else        { src = bwi + n * 128 + (k0 - 128); sgn = -1.f; }
        } else {
            if (k0 < 128) src = bwi + (n - 64) * 128 + k0;
            else          src = bwr + (n - 64) * 128 + (k0 - 128);
        }
        float4 v0 = *(const float4*)src;
        float4 v1 = *(const float4*)(src + 4);
        float vv[8] = {v0.x,v0.y,v0.z,v0.w,v1.x,v1.y,v1.z,v1.w};
        unsigned short h[8], l[8];
        #pragma unroll
        for (int j = 0; j < 8; j++) split_bf16(vv[j] * sgn, h[j], l[j]);
        #pragma unroll
        for (int j = 0; j < 8; j++) { wbhi[f*8+j] = h[j]; wblo[f*8+j] = l[j]; }
    } else {
        int f = tid - 4096;
        int lane = f & 63, ks = (f >> 6) & 3, nt = (f >> 8) & 3, w = f >> 10;
        int l15 = lane & 15, quad = lane >> 4;
        int n = w * 64 + nt * 16 + l15;
        int d = (n < 128) ? n : (n - 128);
        int k0 = ks * 32 + quad * 8;
        unsigned short h[8];
        #pragma unroll
        for (int j = 0; j < 8; j++) {
            int k = k0 + j, col = k >> 1;
            float val;
            if (n < 128) val = (k & 1) ? -cwi[d * 64 + col] : cwr[d * 64 + col];
            else         val = (k & 1) ?  cwr[d * 64 + col] : cwi[d * 64 + col];
            unsigned short hh, hl; split_bf16(val, hh, hl);
            h[j] = hh;
        }
        #pragma unroll
        for (int j = 0; j < 8; j++) wchi[f*8+j] = h[j];
    }
}

// ============================================================================
// FUSED persistent cooperative kernel: g1 + scanB (lookback) + scanC + yGEMM.
// Grid = 1024 blocks (4/CU), block = (bg, chunk-pair). Bx never leaves LDS.
// U row layout (156 dwords = 624 B/row, 64 rows):
//   dwords 0..7   : comb slots (phase A transient)
//   dwords 28..91 : bx vr[n]  (phase A -> phase C)
//   dwords 92..155: bx vi[n]
//   h-frags (phase C, overlays same row after bx row consumed):
//     Ahi = shorts [0..151], Alo = shorts [152..303] (row stride 312 shorts)
// Staging (phase A transient, per chunk): flat shorts,
//   hi[r][col] = SH[r*264+col], lo at +8448 shorts (33,792 B).
// ============================================================================
#define UROW 156
__global__ __launch_bounds__(256, 4) void k_fused(
    const float* __restrict__ xr, const float* __restrict__ xi,
    const float* __restrict__ dtw, const float* __restrict__ dtb,
    const float* __restrict__ logAm, const float* __restrict__ Aph,
    const unsigned short* __restrict__ wbhi, const unsigned short* __restrict__ wblo,
    const unsigned short* __restrict__ wchi,
    float4* __restrict__ trans,
    float* __restrict__ out)
{
    __shared__ __align__(16) unsigned U[64 * UROW];   // 39,936 B
    __shared__ float dms[64], dps[64];                // +512 B = 40,448 B
    float* Uf = (float*)U;
    unsigned short* SH = (unsigned short*)U;

    const int t = threadIdx.x;
    const int lane = t & 63, w = t >> 6;
    const int l15 = lane & 15, quad = lane >> 4;
    const int bg = blockIdx.x >> 5, cp = blockIdx.x & 31;
    const int g = bg & 7, b = bg >> 3;
    const int cA = cp * 2;

    const float b0 = dtb[0], b1 = dtb[1];
    const float nla = -logf(1.0f + __expf(logAm[g * N_ + lane]));
    const float aph = Aph[g * N_ + lane];

    f32x4 acc[2][2][2];   // [chunk][ms][nt]
    #pragma unroll
    for (int q = 0; q < 2; q++)
        #pragma unroll
        for (int a = 0; a < 2; a++)
            #pragma unroll
            for (int bq = 0; bq < 2; bq++)
                acc[q][a][bq] = (f32x4){0.f, 0.f, 0.f, 0.f};

    // ------------------------- Phase A: dt + Bx GEMM -------------------------
    #pragma unroll 1
    for (int q = 0; q < 2; q++) {
        const int c = cA + q;
        const float* xrb = xr + ((size_t)(b * S_ + c * CLEN) * G_ + g) * 128;
        const float* xib = xi + ((size_t)(b * S_ + c * CLEN) * G_ + g) * 128;
        const int q16 = t & 15;
        #pragma unroll
        for (int i = 0; i < 2; i++) {
            const int m = (t >> 4) + 16 * i;
            const float* src = (q16 < 8) ? (xrb + m * 1024 + q16 * 16)
                                         : (xib + m * 1024 + (q16 - 8) * 16);
            float4 v0 = ((const float4*)src)[0];
            float4 v1 = ((const float4*)src)[1];
            float4 v2 = ((const float4*)src)[2];
            float4 v3 = ((const float4*)src)[3];
            const float* w0p = dtw + q16 * 16;
            const float* w1p = dtw + 256 + q16 * 16;
            float pm = dot4(v0, ((const float4*)w0p)[0]) + dot4(v1, ((const float4*)w0p)[1])
                     + dot4(v2, ((const float4*)w0p)[2]) + dot4(v3, ((const float4*)w0p)[3]);
            float pp = dot4(v0, ((const float4*)w1p)[0]) + dot4(v1, ((const float4*)w1p)[1])
                     + dot4(v2, ((const float4*)w1p)[2]) + dot4(v3, ((const float4*)w1p)[3]);
            uint2 h2, l2;
            split4_pk(v0, h2, l2);
            *(uint2*)&SH[m * 264 + q16 * 16 + 0]        = h2;
            *(uint2*)&SH[8448 + m * 264 + q16 * 16 + 0] = l2;
            split4_pk(v1, h2, l2);
            *(uint2*)&SH[m * 264 + q16 * 16 + 4]        = h2;
            *(uint2*)&SH[8448 + m * 264 + q16 * 16 + 4] = l2;
            split4_pk(v2, h2, l2);
            *(uint2*)&SH[m * 264 + q16 * 16 + 8]        = h2;
            *(uint2*)&SH[8448 + m * 264 + q16 * 16 + 8] = l2;
            split4_pk(v3, h2, l2);
            *(uint2*)&SH[m * 264 + q16 * 16 + 12]        = h2;
            *(uint2*)&SH[8448 + m * 264 + q16 * 16 + 12] = l2;
            #pragma unroll
            for (int msk = 8; msk >= 1; msk >>= 1) {
                pm += __shfl_xor(pm, msk);
                pp += __shfl_xor(pp, msk);
            }
            if (q16 == 0) {
                float dm = fminf(fmaxf(__expf(pm + b0), 1e-4f), 2.0f);
                float dp = fminf(fmaxf(__expf(pp + b1), 1e-4f), 2.0f);
                dms[q * 32 + m] = dm; dps[q * 32 + m] = dp;
            }
        }
        __syncthreads();
        #pragma unroll
        for (int ks = 0; ks < 8; ks++) {
            bf16x8 wh0 = ((const bf16x8*)wbhi)[((w * 2 + 0) * 8 + ks) * 64 + lane];
            bf16x8 wl0 = ((const bf16x8*)wblo)[((w * 2 + 0) * 8 + ks) * 64 + lane];
            bf16x8 wh1 = ((const bf16x8*)wbhi)[((w * 2 + 1) * 8 + ks) * 64 + lane];
            bf16x8 wl1 = ((const bf16x8*)wblo)[((w * 2 + 1) * 8 + ks) * 64 + lane];
            #pragma unroll
            for (int ms = 0; ms < 2; ms++) {
                const int ro = (ms * 16 + l15) * 264 + ks * 32 + quad * 8;
                bf16x8 ah = *(const bf16x8*)&SH[ro];
                bf16x8 al = *(const bf16x8*)&SH[8448 + ro];
                acc[q][ms][0] = MFMA16(al, wh0, acc[q][ms][0]);
                acc[q][ms][0] = MFMA16(ah, wl0, acc[q][ms][0]);
                acc[q][ms][0] = MFMA16(ah, wh0, acc[q][ms][0]);
                acc[q][ms][1] = MFMA16(al, wh1, acc[q][ms][1]);
                acc[q][ms][1] = MFMA16(ah, wl1, acc[q][ms][1]);
                acc[q][ms][1] = MFMA16(ah, wh1, acc[q][ms][1]);
            }
        }
        __syncthreads();   // staging reads done (next chunk restages / bx write)
    }

    // bx (scaled by dt_mag) -> U rows (overwrites staging region)
    #pragma unroll
    for (int q = 0; q < 2; q++)
        #pragma unroll
        for (int ms = 0; ms < 2; ms++)
            #pragma unroll
            for (int nt = 0; nt < 2; nt++) {
                const int n = w * 32 + nt * 16 + l15;
                #pragma unroll
                for (int r = 0; r < 4; r++) {
                    const int m32 = ms * 16 + quad * 4 + r;
                    Uf[(q * 32 + m32) * UROW + 28 + n] =
                        acc[q][ms][nt][r] * dms[q * 32 + m32];
                }
            }
    __syncthreads();

    // compose chunk transitions: wave pair (2q, 2q+1); even=steps 0..15, odd=16..31
    {
        const int q = w >> 1, half = w & 1;
        float Ar = 1.f, Ai = 0.f, Br = 0.f, Bi = 0.f;
        #pragma unroll
        for (int tt = 0; tt < 16; tt++) {
            const int m = q * 32 + half * 16 + tt;
            float dm = dms[m], dp = dps[m];
            float am  = __expf(dm * nla);
            float ang = dp * aph;
            float cr = am * __cosf(ang), ci = am * __sinf(ang);
            float vr = Uf[m * UROW + 28 + lane];
            float vi = Uf[m * UROW + 92 + lane];
            float nAr = cr * Ar - ci * Ai;
            float nAi = cr * Ai + ci * Ar;
            float nBr = cr * Br - ci * Bi + vr;
            float nBi = cr * Bi + ci * Br + vi;
            Ar = nAr; Ai = nAi; Br = nBr; Bi = nBi;
        }
        if (half == 0)
            *(float4*)&Uf[lane * UROW + 4 * q] = make_float4(Ar, Ai, Br, Bi);
        __syncthreads();
        if (half == 1) {
            float4 c0 = *(float4*)&Uf[lane * UROW + 4 * q];
            float fAr = Ar * c0.x - Ai * c0.y;
            float fAi = Ar * c0.y + Ai * c0.x;
            float fBr = Ar * c0.z - Ai * c0.w + Br;
            float fBi = Ar * c0.w + Ai * c0.z + Bi;
            trans[(bg * CH + cA + q) * 64 + lane] = make_float4(fAr, fAi, fBr, fBi);
        }
    }

    cg::this_grid().sync();

    // --------- Phase B: per-block lookback + Phase C scan (wave 0) ----------
    if (w == 0) {
        float shr = 0.f, shi = 0.f;
        const float4* tp = trans + (size_t)(bg * CH) * 64 + lane;
        int cc = 0;
        while (cc + 8 <= cA) {
            float4 T[8];
            #pragma unroll
            for (int k = 0; k < 8; k++) T[k] = tp[(cc + k) * 64];
            #pragma unroll
            for (int k = 0; k < 8; k++) {
                float nr = T[k].x * shr - T[k].y * shi + T[k].z;
                float ni = T[k].x * shi + T[k].y * shr + T[k].w;
                shr = nr; shi = ni;
            }
            float nrm = sqrtf(shr * shr + shi * shi + 1e-8f);
            float sc = fminf(nrm, 100.f) / nrm;
            shr *= sc; shi *= sc;
            cc += 8;
        }
        for (; cc < cA; cc++) {
            float4 T = tp[cc * 64];
            float nr = T.x * shr - T.y * shi + T.z;
            float ni = T.x * shi + T.y * shr + T.w;
            shr = nr; shi = ni;
        }
        // 64-step scan over both chunks; h-frags overlay bx rows (read-then-write)
        const bool rnB = (((cA + 1) & 7) == 7);
        #pragma unroll 8
        for (int tt = 0; tt < 64; tt++) {
            float dm = dms[tt], dp = dps[tt];
            float am  = __expf(dm * nla);
            float ang = dp * aph;
            float cr = am * __cosf(ang), ci = am * __sinf(ang);
            float vr = Uf[tt * UROW + 28 + lane];
            float vi = Uf[tt * UROW + 92 + lane];
            float nr = cr * shr - ci * shi + vr;
            float ni = cr * shi + ci * shr + vi;
            if (rnB && tt == 63) {
                float nrm = sqrtf(nr * nr + ni * ni + 1e-8f);
                float scale = fminf(nrm, 100.0f) / nrm;
                nr *= scale; ni *= scale;
            }
            shr = nr; shi = ni;
            unsigned hp = pk_bf16(shr, shi);
            float rr = shr - __uint_as_float(hp << 16);
            float ri = shi - __uint_as_float(hp & 0xFFFF0000u);
            unsigned lp = pk_bf16(rr, ri);
            *(unsigned*)&SH[tt * 312 + 2 * lane]       = hp;
            *(unsigned*)&SH[tt * 312 + 152 + 2 * lane] = lp;
        }
    }
    __syncthreads();

    // ------------------------- Phase C: y GEMM ------------------------------
    #pragma unroll 1
    for (int p = 0; p < 2; p++) {
        f32x4 a2[4][2];
        #pragma unroll
        for (int a = 0; a < 4; a++)
            #pragma unroll
            for (int bq = 0; bq < 2; bq++)
                a2[a][bq] = (f32x4){0.f, 0.f, 0.f, 0.f};
        #pragma unroll
        for (int ks = 0; ks < 4; ks++) {
            bf16x8 wc0 = ((const bf16x8*)wchi)[((w * 4 + p * 2 + 0) * 4 + ks) * 64 + lane];
            bf16x8 wc1 = ((const bf16x8*)wchi)[((w * 4 + p * 2 + 1) * 4 + ks) * 64 + lane];
            #pragma unroll
            for (int ms = 0; ms < 4; ms++) {
                const int ro = (ms * 16 + l15) * 312 + ks * 32 + quad * 8;
                bf16x8 ah = *(const bf16x8*)&SH[ro];
                bf16x8 al = *(const bf16x8*)&SH[ro + 152];
                a2[ms][0] = MFMA16(al, wc0, a2[ms][0]);
                a2[ms][0] = MFMA16(ah, wc0, a2[ms][0]);
                a2[ms][1] = MFMA16(al, wc1, a2[ms][1]);
                a2[ms][1] = MFMA16(ah, wc1, a2[ms][1]);
            }
        }
        #pragma unroll
        for (int ms = 0; ms < 4; ms++)
            #pragma unroll
            for (int ntl = 0; ntl < 2; ntl++) {
                const int nn = (w * 4 + p * 2 + ntl) * 16 + l15;
                float* dst = (nn < 128) ? (out + nn) : (out + YOFF + (nn - 128));
                #pragma unroll
                for (int r = 0; r < 4; r++) {
                    const int ml = ms * 16 + quad * 4 + r;          // 0..63
                    const int srow = (b * S_ + cA * CLEN + ml) * G_ + g;
                    dst[(size_t)srow * 128] = a2[ms][ntl][r];
                }
            }
    }
}

// ======================= FALLBACK PATH (round-3 kernels) =====================
#define LDK1 280
__global__ __launch_bounds__(256, 4) void k_g1(
    const float* __restrict__ xr, const float* __restrict__ xi,
    const float* __restrict__ dtw, const float* __restrict__ dtb,
    const float* __restrict__ logAm, const float* __restrict__ Aph,
    const unsigned short* __restrict__ wbhi, const unsigned short* __restrict__ wblo,
    float* __restrict__ bxr, float* __restrict__ bxi,
    float* __restrict__ dt_mag, float* __restrict__ dt_ph,
    float4* __restrict__ trans)
{
    __shared__ __align__(16) unsigned short Ahi[32 * LDK1];
    __shared__ __align__(16) unsigned short Alo[32 * LDK1];
    __shared__ float dms[32], dps[32];
    __shared__ float4 comb[64];
    float* bxs = (float*)Ahi;
    const int t = threadIdx.x;
    const int lane = t & 63, w = t >> 6;
    const int l15 = lane & 15, quad = lane >> 4;
    const int bg = blockIdx.x >> 6, c = blockIdx.x & 63;
    const int g = bg & 7, b = bg >> 3;
    const int crow = (bg * CH + c) * CLEN;

    const int kq = t & 31, k4 = kq * 4;
    float4 w0r = *(const float4*)(dtw + k4);
    float4 w0i = *(const float4*)(dtw + 128 + k4);
    float4 w1r = *(const float4*)(dtw + 256 + k4);
    float4 w1i = *(const float4*)(dtw + 384 + k4);
    float b0 = dtb[0], b1 = dtb[1];
    float nla = -logf(1.0f + __expf(logAm[g * N_ + lane]));
    float aph = Aph[g * N_ + lane];

    const int s0 = c * CLEN;
    const float* xrb = xr + ((size_t)(b * S_ + s0) * G_ + g) * 128;
    const float* xib = xi + ((size_t)(b * S_ + s0) * G_ + g) * 128;

    float pm[4], pp[4];
    #pragma unroll
    for (int i = 0; i < 4; i++) {
        int f = t + 256 * i;
        int m = f >> 5, kk = f & 31;
        float4 a  = ((const float4*)(xrb + m * 1024))[kk];
        float4 bb = ((const float4*)(xib + m * 1024))[kk];
        uint2 h2, l2;
        split4_pk(a, h2, l2);
        *(uint2*)&Ahi[m * LDK1 + kk * 4] = h2;
        *(uint2*)&Alo[m * LDK1 + kk * 4] = l2;
        split4_pk(bb, h2, l2);
        *(uint2*)&Ahi[m * LDK1 + 128 + kk * 4] = h2;
        *(uint2*)&Alo[m * LDK1 + 128 + kk * 4] = l2;
        pm[i] = dot4(a, w0r) + dot4(bb, w0i);
        pp[i] = dot4(a, w1r) + dot4(bb, w1i);
    }
    #pragma unroll
    for (int i = 0; i < 4; i++) {
        float vm = pm[i], vp = pp[i];
        #pragma unroll
        for (int msk = 16; msk >= 1; msk >>= 1) {
            vm += __shfl_xor(vm, msk);
            vp += __shfl_xor(vp, msk);
        }
        if ((t & 31) == 0) {
            int m = (t >> 5) + 8 * i;
            float dm = fminf(fmaxf(__expf(vm + b0), 1e-4f), 2.0f);
            float dp = fminf(fmaxf(__expf(vp + b1), 1e-4f), 2.0f);
            dms[m] = dm; dps[m] = dp;
            dt_mag[crow + m] = dm; dt_ph[crow + m] = dp;
        }
    }
    __syncthreads();

    f32x4 acc[2][2];
    #pragma unroll
    for (int a = 0; a < 2; a++)
        #pragma unroll
        for (int bq = 0; bq < 2; bq++)
            acc[a][bq] = (f32x4){0.f, 0.f, 0.f, 0.f};
    #pragma unroll
    for (int ks = 0; ks < 8; ks++) {
        bf16x8 wh0 = ((const bf16x8*)wbhi)[((w * 2 + 0) * 8 + ks) * 64 + lane];
        bf16x8 wl0 = ((const bf16x8*)wblo)[((w * 2 + 0) * 8 + ks) * 64 + lane];
        bf16x8 wh1 = ((const bf16x8*)wbhi)[((w * 2 + 1) * 8 + ks) * 64 + lane];
        bf16x8 wl1 = ((const bf16x8*)wblo)[((w * 2 + 1) * 8 + ks) * 64 + lane];
        #pragma unroll
        for (int ms = 0; ms < 2; ms++) {
            int arow = (ms * 16 + l15) * LDK1 + quad * 8;
            bf16x8 ah = *(const bf16x8*)&Ahi[arow + ks * 32];
            bf16x8 al = *(const bf16x8*)&Alo[arow + ks * 32];
            acc[ms][0] = MFMA16(al, wh0, acc[ms][0]);
            acc[ms][0] = MFMA16(ah, wl0, acc[ms][0]);
            acc[ms][0] = MFMA16(ah, wh0, acc[ms][0]);
            acc[ms][1] = MFMA16(al, wh1, acc[ms][1]);
            acc[ms][1] = MFMA16(ah, wl1, acc[ms][1]);
            acc[ms][1] = MFMA16(ah, wh1, acc[ms][1]);
        }
    }
    __syncthreads();

    #pragma unroll
    for (int ms = 0; ms < 2; ms++)
        #pragma unroll
        for (int nt = 0; nt < 2; nt++) {
            int n = w * 32 + nt * 16 + l15;
            float* dstg = (n < 64) ? bxr : bxi;
            int nn = n & 63;
            #pragma unroll
            for (int r = 0; r < 4; r++) {
                int m = ms * 16 + quad * 4 + r;
                float v = acc[ms][nt][r] * dms[m];
                dstg[(crow + m) * 64 + nn] = v;
                bxs[m * 132 + n] = v;
            }
        }
    __syncthreads();

    float Ar = 1.f, Ai = 0.f, Br = 0.f, Bi = 0.f;
    if (w < 2) {
        int base = w * 16;
        #pragma unroll
        for (int tt = 0; tt < 16; tt++) {
            int m = base + tt;
            float dm = dms[m], dp = dps[m];
            float am  = __expf(dm * nla);
            float ang = dp * aph;
            float cr = am * __cosf(ang), ci = am * __sinf(ang);
            float vr = bxs[m * 132 + lane], vi = bxs[m * 132 + 64 + lane];
            float nAr = cr * Ar - ci * Ai;
            float nAi = cr * Ai + ci * Ar;
            float nBr = cr * Br - ci * Bi + vr;
            float nBi = cr * Bi + ci * Br + vi;
            Ar = nAr; Ai = nAi; Br = nBr; Bi = nBi;
        }
        if (w == 0) comb[lane] = make_float4(Ar, Ai, Br, Bi);
    }
    __syncthreads();
    if (w == 1) {
        float4 c0 = comb[lane];
        float fAr = Ar * c0.x - Ai * c0.y;
        float fAi = Ar * c0.y + Ai * c0.x;
        float fBr = Ar * c0.z - Ai * c0.w + Br;
        float fBi = Ar * c0.w + Ai * c0.z + Bi;
        trans[(bg * CH + c) * 64 + lane] = make_float4(fAr, fAi, fBr, fBi);
    }
}

__global__ __launch_bounds__(256) void k_scanB2(const float4* __restrict__ trans,
    float2* __restrict__ hstart)
{
    int w = threadIdx.x >> 6, lane = threadIdx.x & 63;
    int W = blockIdx.x * 4 + w;
    int bg = W >> 3;
    int n  = ((W & 7) << 3) + (lane & 7);
    int j  = lane >> 3;
    float pAr[8], pAi[8], pBr[8], pBi[8];
    float Ar = 1.f, Ai = 0.f, Br = 0.f, Bi = 0.f;
    const float4* tp = trans + (bg * CH + j * 8) * 64 + n;
    #pragma unroll
    for (int k = 0; k < 8; k++) {
        pAr[k] = Ar; pAi[k] = Ai; pBr[k] = Br; pBi[k] = Bi;
        float4 T = tp[k * 64];
        float nAr = T.x * Ar - T.y * Ai;
        float nAi = T.x * Ai + T.y * Ar;
        float nBr = T.x * Br - T.y * Bi + T.z;
        float nBi = T.x * Bi + T.y * Br + T.w;
        Ar = nAr; Ai = nAi; Br = nBr; Bi = nBi;
    }
    float hr = 0.f, hi = 0.f, mhr = 0.f, mhi = 0.f;
    #pragma unroll
    for (int j2 = 0; j2 < 8; j2++) {
        if (j2 == j) { mhr = hr; mhi = hi; }
        int src = j2 * 8 + (lane & 7);
        float sAr = __shfl(Ar, src), sAi = __shfl(Ai, src);
        float sBr = __shfl(Br, src), sBi = __shfl(Bi, src);
        float nr = sAr * hr - sAi * hi + sBr;
        float ni = sAr * hi + sAi * hr + sBi;
        float nrm = sqrtf(nr * nr + ni * ni + 1e-8f);
        float sc = fminf(nrm, 100.f) / nrm;
        hr = nr * sc; hi = ni * sc;
    }
    float2* hp = hstart + (bg * CH + j * 8) * 64 + n;
    #pragma unroll
    for (int k = 0; k < 8; k++) {
        float hsr = pAr[k] * mhr - pAi[k] * mhi + pBr[k];
        float hsi = pAr[k] * mhi + pAi[k] * mhr + pBi[k];
        hp[k * 64] = make_float2(hsr, hsi);
    }
}

#define LDK2 152
__global__ __launch_bounds__(256, 6) void k_sg2(
    const float* __restrict__ bxr, const float* __restrict__ bxi,
    const float* __restrict__ dt_mag, const float* __restrict__ dt_ph,
    const float* __restrict__ logAm, const float* __restrict__ Aph,
    const float2* __restrict__ hstart,
    const unsigned short* __restrict__ wchi,
    float* __restrict__ out)
{
    __shared__ __align__(16) unsigned short Ahi[32 * LDK2];
    __shared__ __align__(16) unsigned short Alo[32 * LDK2];
    const int t = threadIdx.x;
    const int lane = t & 63, w = t >> 6;
    const int l15 = lane & 15, quad = lane >> 4;
    const int bg = blockIdx.x >> 6, c = blockIdx.x & 63;
    const int g = bg & 7, b = bg >> 3;

    if (w == 0) {
        const int n = lane;
        float nla = -logf(1.0f + __expf(logAm[g * N_ + n]));
        float aph = Aph[g * N_ + n];
        float2 h0 = hstart[(bg * CH + c) * 64 + n];
        float hr = h0.x, hi = h0.y;
        const bool rn = ((c & 7) == 7);
        const int base = (bg * CH + c) * CLEN;
        #pragma unroll 8
        for (int tt = 0; tt < CLEN; tt++) {
            float dm = dt_mag[base + tt], dp = dt_ph[base + tt];
            float am  = __expf(dm * nla);
            float ang = dp * aph;
            float cr = am * __cosf(ang), ci = am * __sinf(ang);
            float vr = bxr[(base + tt) * 64 + n];
            float vi = bxi[(base + tt) * 64 + n];
            float nr = cr * hr - ci * hi + vr;
            float ni = cr * hi + ci * hr + vi;
            if (rn && tt == CLEN - 1) {
                float nrm = sqrtf(nr * nr + ni * ni + 1e-8f);
                float scale = fminf(nrm, 100.0f) / nrm;
                nr *= scale; ni *= scale;
            }
            hr = nr; hi = ni;
            unsigned hp = pk_bf16(hr, hi);
            float rr = hr - __uint_as_float(hp << 16);
            float ri = hi - __uint_as_float(hp & 0xFFFF0000u);
            unsigned lp = pk_bf16(rr, ri);
            *(unsigned*)&Ahi[tt * LDK2 + 2 * n] = hp;
            *(unsigned*)&Alo[tt * LDK2 + 2 * n] = lp;
        }
    }
    __syncthreads();

    f32x4 acc[2][4];
    #pragma unroll
    for (int a = 0; a < 2; a++)
        #pragma unroll
        for (int bq = 0; bq < 4; bq++)
            acc[a][bq] = (f32x4){0.f, 0.f, 0.f, 0.f};
    #pragma unroll
    for (int ks = 0; ks < 4; ks++) {
        bf16x8 wc0 = ((const bf16x8*)wchi)[((w * 4 + 0) * 4 + ks) * 64 + lane];
        bf16x8 wc1 = ((const bf16x8*)wchi)[((w * 4 + 1) * 4 + ks) * 64 + lane];
        bf16x8 wc2 = ((const bf16x8*)wchi)[((w * 4 + 2) * 4 + ks) * 64 + lane];
        bf16x8 wc3 = ((const bf16x8*)wchi)[((w * 4 + 3) * 4 + ks) * 64 + lane];
        #pragma unroll
        for (int ms = 0; ms < 2; ms++) {
            int arow = (ms * 16 + l15) * LDK2 + quad * 8;
            bf16x8 ah = *(const bf16x8*)&Ahi[arow + ks * 32];
            bf16x8 al = *(const bf16x8*)&Alo[arow + ks * 32];
            acc[ms][0] = MFMA16(al, wc0, acc[ms][0]);
            acc[ms][0] = MFMA16(ah, wc0, acc[ms][0]);
            acc[ms][1] = MFMA16(al, wc1, acc[ms][1]);
            acc[ms][1] = MFMA16(ah, wc1, acc[ms][1]);
            acc[ms][2] = MFMA16(al, wc2, acc[ms][2]);
            acc[ms][2] = MFMA16(ah, wc2, acc[ms][2]);
            acc[ms][3] = MFMA16(al, wc3, acc[ms][3]);
            acc[ms][3] = MFMA16(ah, wc3, acc[ms][3]);
        }
    }
    #pragma unroll
    for (int ms = 0; ms < 2; ms++)
        #pragma unroll
        for (int nt = 0; nt < 4; nt++) {
            int nn = w * 64 + nt * 16 + l15;
            float* dst = (nn < 128) ? (out + nn) : (out + YOFF + (nn - 128));
            #pragma unroll
            for (int r = 0; r < 4; r++) {
                int tt2 = ms * 16 + quad * 4 + r;
                int srow = (b * S_ + c * CLEN + tt2) * G_ + g;
                dst[srow * 128] = acc[ms][nt][r];
            }
        }
}

extern "C" void kernel_launch(void* const* d_in, const int* in_sizes, int n_in,
                              void* d_out, int out_size, void* d_ws, size_t ws_size,
                              hipStream_t stream) {
    (void)in_sizes; (void)n_in; (void)out_size; (void)ws_size;
    const float* xr    = (const float*)d_in[0];
    const float* xi    = (const float*)d_in[1];
    const float* logAm = (const float*)d_in[2];
    const float* Aph   = (const float*)d_in[3];
    const float* bwr   = (const float*)d_in[4];
    const float* bwi   = (const float*)d_in[5];
    const float* cwr   = (const float*)d_in[6];
    const float* cwi   = (const float*)d_in[7];
    const float* dtw   = (const float*)d_in[8];
    const float* dtb   = (const float*)d_in[9];
    float* out = (float*)d_out;
    float* ws  = (float*)d_ws;

    float*  dt_mag = ws;                      // 65536
    float*  dt_ph  = ws + 65536;              // 65536
    float*  bxr    = ws + 131072;             // 4194304
    float*  bxi    = bxr + 4194304;           // 4194304
    float4* trans  = (float4*)(ws + 8519680); // 131072 float4
    float2* hstart = (float2*)(ws + 9043968); // 131072 float2
    unsigned short* wbhi = (unsigned short*)(ws + 9306112); // 32768 shorts
    unsigned short* wblo = wbhi + 32768;
    unsigned short* wchi = wblo + 32768;

    hipLaunchKernelGGL(k_prep, dim3(32), dim3(256), 0, stream,
                       bwr, bwi, cwr, cwi, wbhi, wblo, wchi);

    // ---- try the fused cooperative path; fall back on any failure ----
    bool fused_ok = false;
    int dev = 0;
    if (hipGetDevice(&dev) == hipSuccess) {
        int coop = 0, ncu = 0, nb = 0;
        hipDeviceGetAttribute(&coop, hipDeviceAttributeCooperativeLaunch, dev);
        hipDeviceGetAttribute(&ncu, hipDeviceAttributeMultiprocessorCount, dev);
        hipError_t oe = hipOccupancyMaxActiveBlocksPerMultiprocessor(
            &nb, reinterpret_cast<const void*>(k_fused), 256, 0);
        if (coop && oe == hipSuccess && (long)nb * (long)ncu >= 1024) {
            const unsigned short* wbhi_c = wbhi;
            const unsigned short* wblo_c = wblo;
            const unsigned short* wchi_c = wchi;
            void* args[] = {
                (void*)&xr, (void*)&xi, (void*)&dtw, (void*)&dtb,
                (void*)&logAm, (void*)&Aph,
                (void*)&wbhi_c, (void*)&wblo_c, (void*)&wchi_c,
                (void*)&trans, (void*)&out
            };
            hipError_t e = hipLaunchCooperativeKernel(
                reinterpret_cast<void*>(k_fused), dim3(1024), dim3(256),
                args, 0, stream);
            if (e == hipSuccess) fused_ok = true;
            else (void)hipGetLastError();
        }
    }

    if (!fused_ok) {
        hipLaunchKernelGGL(k_g1, dim3((B_ * G_) * 64), dim3(256), 0, stream,
                           xr, xi, dtw, dtb, logAm, Aph, wbhi, wblo,
                           bxr, bxi, dt_mag, dt_ph, trans);
        hipLaunchKernelGGL(k_scanB2, dim3(64), dim3(256), 0, stream,
                           trans, hstart);
        hipLaunchKernelGGL(k_sg2, dim3((B_ * G_) * 64), dim3(256), 0, stream,
                           bxr, bxi, dt_mag, dt_ph, logAm, Aph, hstart, wchi, out);
    }
}